// Round 11
// baseline (11748.775 us; speedup 1.0000x reference)
//
#include <hip/hip_runtime.h>

#define HDIM 32

typedef float v2f __attribute__((ext_vector_type(2)));
typedef unsigned int v2u __attribute__((ext_vector_type(2)));

#define KEEPF(v) asm("" : "+v"(v))

__device__ inline float fast_exp2(float x) {
#if __has_builtin(__builtin_amdgcn_exp2f)
  return __builtin_amdgcn_exp2f(x);
#else
  return exp2f(x);
#endif
}
__device__ inline float fast_rcp(float x) {
#if __has_builtin(__builtin_amdgcn_rcpf)
  return __builtin_amdgcn_rcpf(x);
#else
  return 1.0f / x;
#endif
}

// permlane32_swap(v,v): r.x = [v.lo|v.lo] (high lanes see low-counterpart),
//                       r.y = [v.hi|v.hi] (low lanes see high-counterpart).
__device__ inline float xchg32_for_high(float a) {
#if __has_builtin(__builtin_amdgcn_permlane32_swap)
  v2u r = __builtin_amdgcn_permlane32_swap(
      __float_as_uint(a), __float_as_uint(a), false, false);
  return __uint_as_float(r.x);
#else
  return __shfl_xor(a, 32);
#endif
}
// Value held by the counterpart lane (lane ^ 32), for any lane.
__device__ inline float from_counterpart(float v, bool low) {
#if __has_builtin(__builtin_amdgcn_permlane32_swap)
  v2u r = __builtin_amdgcn_permlane32_swap(
      __float_as_uint(v), __float_as_uint(v), false, false);
  return low ? __uint_as_float(r.y) : __uint_as_float(r.x);
#else
  return __shfl_xor(v, 32);
#endif
}
__device__ inline float sum_halves(float p) {
#if __has_builtin(__builtin_amdgcn_permlane32_swap)
  v2u r = __builtin_amdgcn_permlane32_swap(
      __float_as_uint(p), __float_as_uint(p), false, false);
  return __uint_as_float(r.x) + __uint_as_float(r.y);
#else
  return p + __shfl_xor(p, 32);
#endif
}

// One wave per batch element. Low lane k owns gate rows (k, 64+k) = (i,g);
// high lane 32+k owns rows (32+k, 96+k) = (f,o). State (c,h) for unit k is
// valid in HIGH lane 32+k.
//
// Matvec (g = W_hh . h + xp), SGPR-free: h is broadcast via 16 ds_bpermute
// regs B_s (low lanes get h[s], high lanes h[16+s]); each lane accumulates
// its own row-pair over its 16-wide K-half (acc SELF) and its counterpart
// lane's row-pair over the same K-half (acc OTHR). The counterpart's OTHR
// partial is the missing K-half of THIS lane's rows: one permlane32_swap
// per component combines them. No readlane -> no SGPR hazards.
__global__ __launch_bounds__(64)
__attribute__((amdgpu_waves_per_eu(1, 1)))
void lstm_fused(
    const float* __restrict__ x,
    const float* __restrict__ h0,
    const float* __restrict__ c0,
    const float* __restrict__ W_ih,
    const float* __restrict__ W_hh,
    const float* __restrict__ b_ih,
    const float* __restrict__ b_hh,
    const float* __restrict__ W_head,
    const float* __restrict__ b_head,
    float* __restrict__ y,
    int T)
{
  const int lane = threadIdx.x;       // 0..63
  const int b    = blockIdx.x;        // batch
  const int k    = lane & 31;
  const int half = lane >> 5;         // 0 = low, 1 = high
  const int m0   = half << 4;         // this lane's K-range start (0 or 16)
  const int j1   = lane;              // own rows
  const int j2   = lane + 64;
  const int j1o  = lane ^ 32;         // counterpart rows
  const int j2o  = (lane ^ 32) + 64;
  const bool low = (half == 0);

  // bpermute byte index: low lanes fetch lane 32+s, high lanes lane 48+s.
  const int bpbase = 128 + (half << 6);

  // Weights: SELF rows (j1,j2) and OTHR rows (j1o,j2o), cols m0..m0+15,
  // packed per column as {row_j1, row_j2}. 32 v2f = 64 VGPRs, pinned.
  v2f Wself[16], Wothr[16];
#pragma unroll
  for (int q = 0; q < 4; ++q) {
    const float4 va = *reinterpret_cast<const float4*>(W_hh + j1  * HDIM + m0 + q * 4);
    const float4 vb = *reinterpret_cast<const float4*>(W_hh + j2  * HDIM + m0 + q * 4);
    const float4 vc = *reinterpret_cast<const float4*>(W_hh + j1o * HDIM + m0 + q * 4);
    const float4 vd = *reinterpret_cast<const float4*>(W_hh + j2o * HDIM + m0 + q * 4);
    Wself[q*4+0][0] = va.x; Wself[q*4+1][0] = va.y; Wself[q*4+2][0] = va.z; Wself[q*4+3][0] = va.w;
    Wself[q*4+0][1] = vb.x; Wself[q*4+1][1] = vb.y; Wself[q*4+2][1] = vb.z; Wself[q*4+3][1] = vb.w;
    Wothr[q*4+0][0] = vc.x; Wothr[q*4+1][0] = vc.y; Wothr[q*4+2][0] = vc.z; Wothr[q*4+3][0] = vc.w;
    Wothr[q*4+0][1] = vd.x; Wothr[q*4+1][1] = vd.y; Wothr[q*4+2][1] = vd.z; Wothr[q*4+3][1] = vd.w;
  }
#pragma unroll
  for (int s = 0; s < 16; ++s) {
    KEEPF(Wself[s][0]); KEEPF(Wself[s][1]);
    KEEPF(Wothr[s][0]); KEEPF(Wothr[s][1]);
  }

  v2f wih;  wih[0]  = W_ih[j1];            wih[1]  = W_ih[j2];
  v2f bias; bias[0] = b_ih[j1] + b_hh[j1]; bias[1] = b_ih[j2] + b_hh[j2];
  KEEPF(wih[0]); KEEPF(wih[1]); KEEPF(bias[0]); KEEPF(bias[1]);
  float wh = W_head[k];
  float bh = b_head[0];
  KEEPF(wh); KEEPF(bh);

  const float LOG2E = 1.4426950408889634f;
  float m2L = low ? (-2.0f * LOG2E) : (-LOG2E);
  float sA  = low ? 2.0f : 1.0f;
  float bA  = low ? -1.0f : 0.0f;
  KEEPF(m2L); KEEPF(sA); KEEPF(bA);

  float h = h0[k];
  float c = c0[k];

  const float* xb = x + (size_t)b * T;
  float*       yb = y + (size_t)b * T;

  __shared__ float hb[32][68];

#pragma unroll 1
  for (int t0 = 0; t0 < T; t0 += 32) {
    float xs[32];
#pragma unroll
    for (int q = 0; q < 8; ++q) {
      float4 v = *reinterpret_cast<const float4*>(xb + t0 + q * 4);
      KEEPF(v.x); KEEPF(v.y); KEEPF(v.z); KEEPF(v.w);
      xs[q * 4 + 0] = v.x; xs[q * 4 + 1] = v.y;
      xs[q * 4 + 2] = v.z; xs[q * 4 + 3] = v.w;
    }

#pragma unroll
    for (int tt = 0; tt < 32; ++tt) {
      const float xt = xs[tt];

      // 16 VGPR broadcasts of h (low: h[s], high: h[16+s]).
      const int hbits = __float_as_int(h);
      float B[16];
#pragma unroll
      for (int s = 0; s < 16; ++s)
        B[s] = __int_as_float(__builtin_amdgcn_ds_bpermute(bpbase + 4 * s, hbits));

      // 4 ILP chains: SELF rows (init = xp) and OTHR rows (init = 0).
      v2f aS0; aS0[0] = fmaf(xt, wih[0], bias[0]); aS0[1] = fmaf(xt, wih[1], bias[1]);
      v2f aS1; aS1[0] = 0.f; aS1[1] = 0.f;
      v2f aO0; aO0[0] = 0.f; aO0[1] = 0.f;
      v2f aO1; aO1[0] = 0.f; aO1[1] = 0.f;
#pragma unroll
      for (int s = 0; s < 16; s += 2) {
        v2f t0v; t0v[0] = B[s];     t0v[1] = B[s];
        v2f t1v; t1v[0] = B[s + 1]; t1v[1] = B[s + 1];
        aS0 = __builtin_elementwise_fma(t0v, Wself[s],     aS0);
        aS1 = __builtin_elementwise_fma(t1v, Wself[s + 1], aS1);
        aO0 = __builtin_elementwise_fma(t0v, Wothr[s],     aO0);
        aO1 = __builtin_elementwise_fma(t1v, Wothr[s + 1], aO1);
      }
      const v2f aS = aS0 + aS1;
      const v2f aO = aO0 + aO1;
      // Counterpart's OTHR partial = missing K-half of OUR rows.
      v2f g;
      g[0] = aS[0] + from_counterpart(aO[0], low);
      g[1] = aS[1] + from_counterpart(aO[1], low);

      // p1 = sigmoid(g1)  (i on low, f on high)
      const float e1 = fast_exp2(g[0] * (-LOG2E));
      const float p1 = fast_rcp(1.0f + e1);
      // p2 = tanh(g2) on low, sigmoid(g2) on high
      const float e2 = fast_exp2(g[1] * m2L);
      const float s2 = fast_rcp(1.0f + e2);
      const float p2 = fmaf(s2, sA, bA);

      const float a  = p1 * p2;              // low: sig(i)*tanh(g)
      const float e  = xchg32_for_high(a);   // high lanes receive low's a

      c = fmaf(p1, c, e);                    // high: sig(f)*c + a
      const float ec = fast_exp2(c * (-2.0f * LOG2E));
      const float tc = fmaf(fast_rcp(1.0f + ec), 2.0f, -1.0f);  // tanh(c)
      h = p2 * tc;                           // high: sig(o)*tanh(c)

      hb[tt][lane] = h * wh;                 // cols 32..63 valid
    }

    // Head: y[t0+r] = sum_k hb[r][32+k] + bh; halves split 16+16 cols,
    // combined with one permlane32_swap.
    {
      const int r = k;
      const float* row = &hb[r][32 + (half << 4)];
      const float4 s0 = *reinterpret_cast<const float4*>(row + 0);
      const float4 s1 = *reinterpret_cast<const float4*>(row + 4);
      const float4 s2 = *reinterpret_cast<const float4*>(row + 8);
      const float4 s3 = *reinterpret_cast<const float4*>(row + 12);
      const float p = ((s0.x + s0.y) + (s0.z + s0.w))
                    + ((s1.x + s1.y) + (s1.z + s1.w))
                    + ((s2.x + s2.y) + (s2.z + s2.w))
                    + ((s3.x + s3.y) + (s3.z + s3.w));
      const float tot = sum_halves(p) + bh;
      if (lane < 32) yb[t0 + r] = tot;
    }
  }
}

extern "C" void kernel_launch(void* const* d_in, const int* in_sizes, int n_in,
                              void* d_out, int out_size, void* d_ws, size_t ws_size,
                              hipStream_t stream) {
  const float* x      = (const float*)d_in[0];
  const float* h0     = (const float*)d_in[1];
  const float* c0     = (const float*)d_in[2];
  const float* W_ih   = (const float*)d_in[3];
  const float* W_hh   = (const float*)d_in[4];
  const float* b_ih   = (const float*)d_in[5];
  const float* b_hh   = (const float*)d_in[6];
  const float* W_head = (const float*)d_in[7];
  const float* b_head = (const float*)d_in[8];
  float* yout = (float*)d_out;

  const int B = 64;
  const int T = in_sizes[0] / B;   // 48384, divisible by 32

  lstm_fused<<<dim3(B), dim3(64), 0, stream>>>(
      x, h0, c0, W_ih, W_hh, b_ih, b_hh, W_head, b_head, yout, T);
}